// Round 1
// baseline (295.842 us; speedup 1.0000x reference)
//
#include <hip/hip_runtime.h>
#include <math.h>

// Problem constants
constexpr int Bn = 2, Ln = 128, Dn = 256, Hn = 256;

// log(expm1(0.01))
#define LR_SHIFT (-4.6001660040607144f)

// Workspace offsets (floats)
constexpr int OFF_Q      = 0;        // [B,L,D]
constexpr int OFF_K      = 65536;    // [B,L,D]
constexpr int OFF_V      = 131072;   // [B,L,D]
constexpr int OFF_X2     = 196608;   // [B,L,H]
constexpr int OFF_GZ1    = 262144;   // [B,L,H]  (holds Z1 between fstage<0> and fstage<2>)
constexpr int OFF_GZ2    = 327680;   // [B,L,D]
constexpr int OFF_XQ     = 393216;   // [B,L,H]
constexpr int OFF_KT     = 458752;   // [B,256,128]  K transposed (feature-major)
constexpr int OFF_A      = 524288;   // [B,L,L]  A = Dm@M (lower-tri)
constexpr int OFF_W1T    = 557056;   // [B,D,H]  W1 transposed
constexpr int OFF_W2T    = 688128;   // [B,H,D]  W2 transposed
constexpr int OFF_MW1T   = 819200;   // [B,D,H]
constexpr int OFF_MW2T   = 950272;   // [B,H,D]
constexpr int OFF_LR     = 1081344;  // [B,L]
constexpr int OFF_PM     = 1081600;  // [B,L] prefix sum of log_mom (inclusive)
constexpr int OFF_PD     = 1081856;  // [B,L] prefix sum of log_wd
constexpr int OFF_MOMCUM = 1082112;  // [B,L]
constexpr int OFF_WDCUM  = 1082368;  // [B,L]
constexpr int OFF_C      = 1082624;  // [B,L]  c = Dm @ mom_cum
constexpr int OFF_LOGM   = 1082880;  // [B,L]
constexpr int OFF_LOGWD  = 1083136;  // [B,L]
constexpr int OFF_X2T    = 1083392;  // [B,256,128]  X2 transposed
// total 1148928 floats ~= 4.6 MB (unchanged)

// Output offsets (floats), tuple order
constexpr int OUT_ZQ2  = 0;       // [B,L,D]
constexpr int OUT_W1P  = 65536;   // [B,H,D]
constexpr int OUT_B1P  = 196608;  // [B,H]
constexpr int OUT_W2P  = 197120;  // [B,D,H]
constexpr int OUT_B2P  = 328192;  // [B,D]
constexpr int OUT_MGW1 = 328704;  // [B,H,D]
constexpr int OUT_MGB1 = 459776;  // [B,H]
constexpr int OUT_MGW2 = 460288;  // [B,D,H]
constexpr int OUT_MGB2 = 591360;  // [B,D]

__device__ __forceinline__ float softplus_f(float z) {
    return fmaxf(z, 0.0f) + log1pf(expf(-fabsf(z)));
}

__device__ __forceinline__ float4 fma4(float s, const float4 w, float4 a) {
    a.x += s * w.x; a.y += s * w.y; a.z += s * w.z; a.w += s * w.w; return a;
}

__device__ __forceinline__ float silu_f(float z) {
    return z / (1.0f + expf(-z));
}

// ---------------------------------------------------------------------------
// k0: transpose W1, W2, mW1, mW2 (each [256,256] per batch) into workspace
// ---------------------------------------------------------------------------
__global__ __launch_bounds__(256) void transpose_kernel(
    const float* __restrict__ W1, const float* __restrict__ W2,
    const float* __restrict__ mW1, const float* __restrict__ mW2,
    float* __restrict__ ws) {
    int z = blockIdx.z; int mat = z >> 1; int b = z & 1;
    const float* src; float* dst;
    if (mat == 0)      { src = W1  + b * 65536; dst = ws + OFF_W1T  + b * 65536; }
    else if (mat == 1) { src = W2  + b * 65536; dst = ws + OFF_W2T  + b * 65536; }
    else if (mat == 2) { src = mW1 + b * 65536; dst = ws + OFF_MW1T + b * 65536; }
    else               { src = mW2 + b * 65536; dst = ws + OFF_MW2T + b * 65536; }
    __shared__ float tile[32][33];
    int tx = threadIdx.x & 31, ty = threadIdx.x >> 5;
    int r0 = blockIdx.y * 32, c0 = blockIdx.x * 32;
    for (int i = 0; i < 32; i += 8)
        tile[ty + i][tx] = src[(r0 + ty + i) * 256 + (c0 + tx)];
    __syncthreads();
    for (int i = 0; i < 32; i += 8)
        dst[(c0 + ty + i) * 256 + (r0 + tx)] = tile[tx][ty + i];
}

// ---------------------------------------------------------------------------
// k1: Q/K/V projection as a tiled GEMM.
// Block = 8 tokens x 64 cols of one matrix; grid (4 ctiles, 32 ttiles, 3 mats).
// Thread = (token = t>>4, col-quad = t&15); per k: 1 float4 W load + 4 FMA.
// Weights streamed once per 8 tokens (vs once per token before).
// ---------------------------------------------------------------------------
__global__ __launch_bounds__(128) void qkv_kernel(
    const float* __restrict__ x,
    const float* __restrict__ Wq, const float* __restrict__ bq,
    const float* __restrict__ Wk, const float* __restrict__ bk,
    const float* __restrict__ Wv, const float* __restrict__ bv,
    float* __restrict__ ws) {
    int mat = blockIdx.z;
    const float* W    = (mat == 0) ? Wq : (mat == 1) ? Wk : Wv;
    const float* bias = (mat == 0) ? bq : (mat == 1) ? bk : bv;
    int outoff = (mat == 0) ? OFF_Q : (mat == 1) ? OFF_K : OFF_V;
    int bl0 = blockIdx.y * 8;      // global token base (0..255)
    int c0  = blockIdx.x * 64;
    int t = threadIdx.x;
    __shared__ float xs[8][260];   // pad: 260 % 32 = 4 -> conflict-free tok groups
    for (int i = t; i < 512; i += 128) {
        int tok = i >> 6, kq = i & 63;
        *(float4*)&xs[tok][kq * 4] = *(const float4*)(x + (bl0 + tok) * 256 + kq * 4);
    }
    __syncthreads();
    int tok = t >> 4, cq = t & 15;
    int c = c0 + 4 * cq;
    const float* Wp = W + c;
    float4 acc = {0, 0, 0, 0};
#pragma unroll 8
    for (int k = 0; k < 256; ++k)
        acc = fma4(xs[tok][k], *(const float4*)(Wp + k * 256), acc);
    float4 bb = *(const float4*)(bias + c);
    acc.x += bb.x; acc.y += bb.y; acc.z += bb.z; acc.w += bb.w;
    *(float4*)(ws + outoff + (bl0 + tok) * 256 + c) = acc;
}

// ---------------------------------------------------------------------------
// k1b: scalar projections (lr / log_mom / log_wd). One wave per token.
// ---------------------------------------------------------------------------
__global__ __launch_bounds__(256) void scalproj_kernel(
    const float* __restrict__ x,
    const float* __restrict__ Wlr, const float* __restrict__ blr,
    const float* __restrict__ Wm, const float* __restrict__ bm,
    const float* __restrict__ Wd, const float* __restrict__ bd,
    float* __restrict__ ws) {
    int t = threadIdx.x;
    int ln = t & 63, wv = t >> 6;
    int bl = blockIdx.x * 4 + wv;   // global token
    float4 xv = *(const float4*)(x + bl * 256 + ln * 4);
    float4 wl = *(const float4*)(Wlr + ln * 4);
    float4 wm = *(const float4*)(Wm + ln * 4);
    float4 wd = *(const float4*)(Wd + ln * 4);
    float s1 = xv.x * wl.x + xv.y * wl.y + xv.z * wl.z + xv.w * wl.w;
    float s2 = xv.x * wm.x + xv.y * wm.y + xv.z * wm.z + xv.w * wm.w;
    float s3 = xv.x * wd.x + xv.y * wd.y + xv.z * wd.z + xv.w * wd.w;
#pragma unroll
    for (int off = 32; off > 0; off >>= 1) {
        s1 += __shfl_xor(s1, off);
        s2 += __shfl_xor(s2, off);
        s3 += __shfl_xor(s3, off);
    }
    if (ln == 0) {
        ws[OFF_LR + bl]    = softplus_f(s1 + blr[0] + LR_SHIFT);
        ws[OFF_LOGM + bl]  = -softplus_f(-(s2 + bm[0]));
        ws[OFF_LOGWD + bl] = -softplus_f(s3 + bd[0]);
    }
}

// ---------------------------------------------------------------------------
// k2: per-batch prefix scans -> Pm, Pd, mom_cum, wd_cum, c
// ---------------------------------------------------------------------------
__global__ __launch_bounds__(128) void scan_kernel(float* __restrict__ ws) {
    int b = blockIdx.x; int t = threadIdx.x;
    __shared__ float sm[128], sd[128], se[128];
    sm[t] = ws[OFF_LOGM + b * Ln + t];
    sd[t] = ws[OFF_LOGWD + b * Ln + t];
    __syncthreads();
    for (int off = 1; off < 128; off <<= 1) {
        float am = (t >= off) ? sm[t - off] : 0.0f;
        float ad = (t >= off) ? sd[t - off] : 0.0f;
        __syncthreads();
        sm[t] += am; sd[t] += ad;
        __syncthreads();
    }
    float pm = sm[t], pd = sd[t];
    ws[OFF_PM + b * Ln + t] = pm;
    ws[OFF_PD + b * Ln + t] = pd;
    ws[OFF_MOMCUM + b * Ln + t] = expf(pm);
    ws[OFF_WDCUM + b * Ln + t]  = expf(pd);
    se[t] = expf(pm - pd);
    __syncthreads();
    for (int off = 1; off < 128; off <<= 1) {
        float a = (t >= off) ? se[t - off] : 0.0f;
        __syncthreads();
        se[t] += a;
        __syncthreads();
    }
    ws[OFF_C + b * Ln + t] = expf(pd) * se[t];
}

// ---------------------------------------------------------------------------
// k3: A = Dm @ M  (lower-tri, per batch)
// ---------------------------------------------------------------------------
__global__ __launch_bounds__(128) void a_kernel(float* __restrict__ ws) {
    int bl = blockIdx.x; int b = bl >> 7; int l = bl & 127;
    int m1 = threadIdx.x;
    const float* Pm = ws + OFF_PM + b * Ln;
    const float* Pd = ws + OFF_PD + b * Ln;
    float a = 0.0f;
    if (m1 <= l) {
        float pdl = Pd[l], pmm1 = Pm[m1];
        float s = 0.0f;
        for (int m = m1; m <= l; ++m)
            s += expf((pdl - Pd[m]) + (Pm[m] - pmm1));
        a = s;
    }
    ws[OFF_A + bl * Ln + m1] = a;
}

// ---------------------------------------------------------------------------
// k4: forward MLP + grads as 3 chained GEMM-tile launches.
// MODE 0: Z1 = K @ W1t + b1 -> Z1 parked in GZ1, X2 = silu(Z1)
// MODE 1: gZ2 = X2 @ W2t + b2 - V
// MODE 2: gX2 = gZ2 @ W2(native); gZ1 = gX2 * silu'(Z1)   (in-place on GZ1)
// Same tile template as qkv_kernel; per-batch weights.
// ---------------------------------------------------------------------------
template <int MODE>
__global__ __launch_bounds__(128) void fstage_kernel(
    const float* __restrict__ W2nat, const float* __restrict__ b1,
    const float* __restrict__ b2, float* __restrict__ ws) {
    int bl0 = blockIdx.y * 8;           // global token (0..255)
    int b = bl0 >> 7;
    int c0 = blockIdx.x * 64;
    const float* in; const float* W;
    if (MODE == 0)      { in = ws + OFF_K;   W = ws + OFF_W1T + b * 65536; }
    else if (MODE == 1) { in = ws + OFF_X2;  W = ws + OFF_W2T + b * 65536; }
    else                { in = ws + OFF_GZ2; W = W2nat + b * 65536; }
    int t = threadIdx.x;
    __shared__ float xs[8][260];
    for (int i = t; i < 512; i += 128) {
        int tok = i >> 6, kq = i & 63;
        *(float4*)&xs[tok][kq * 4] = *(const float4*)(in + (bl0 + tok) * 256 + kq * 4);
    }
    __syncthreads();
    int tok = t >> 4, cq = t & 15;
    int c = c0 + 4 * cq;
    const float* Wp = W + c;
    float4 acc = {0, 0, 0, 0};
#pragma unroll 8
    for (int k = 0; k < 256; ++k)
        acc = fma4(xs[tok][k], *(const float4*)(Wp + k * 256), acc);
    int row = (bl0 + tok) * 256 + c;
    if (MODE == 0) {
        float4 bb = *(const float4*)(b1 + b * 256 + c);
        float4 z = {acc.x + bb.x, acc.y + bb.y, acc.z + bb.z, acc.w + bb.w};
        *(float4*)(ws + OFF_GZ1 + row) = z;        // park Z1
        float4 s = {silu_f(z.x), silu_f(z.y), silu_f(z.z), silu_f(z.w)};
        *(float4*)(ws + OFF_X2 + row) = s;
    } else if (MODE == 1) {
        float4 bb = *(const float4*)(b2 + b * 256 + c);
        float4 v = *(const float4*)(ws + OFF_V + row);
        float4 g = {acc.x + bb.x - v.x, acc.y + bb.y - v.y,
                    acc.z + bb.z - v.z, acc.w + bb.w - v.w};
        *(float4*)(ws + OFF_GZ2 + row) = g;
    } else {
        float4 z = *(const float4*)(ws + OFF_GZ1 + row);   // Z1
        float4 g;
        {
            float sg = 1.0f / (1.0f + expf(-z.x));
            g.x = acc.x * (sg * (1.0f + z.x * (1.0f - sg)));
            sg = 1.0f / (1.0f + expf(-z.y));
            g.y = acc.y * (sg * (1.0f + z.y * (1.0f - sg)));
            sg = 1.0f / (1.0f + expf(-z.z));
            g.z = acc.z * (sg * (1.0f + z.z * (1.0f - sg)));
            sg = 1.0f / (1.0f + expf(-z.w));
            g.w = acc.w * (sg * (1.0f + z.w * (1.0f - sg)));
        }
        *(float4*)(ws + OFF_GZ1 + row) = g;        // final gZ1
    }
}

// ---------------------------------------------------------------------------
// k5: transpose K and X2 ([B,128,256] -> [B,256,128]) for coalesced scores
// ---------------------------------------------------------------------------
__global__ __launch_bounds__(256) void transpkx_kernel(float* __restrict__ ws) {
    int z = blockIdx.z; int b = z & 1; int mat = z >> 1;
    const float* src = ws + (mat ? OFF_X2 : OFF_K) + b * 32768;
    float* dst = ws + (mat ? OFF_X2T : OFF_KT) + b * 32768;
    __shared__ float tile[32][33];
    int tx = threadIdx.x & 31, ty = threadIdx.x >> 5;
    int l0 = blockIdx.y * 32, n0 = blockIdx.x * 32;
    for (int i = 0; i < 32; i += 8)
        tile[ty + i][tx] = src[(l0 + ty + i) * 256 + (n0 + tx)];
    __syncthreads();
    for (int i = 0; i < 32; i += 8)
        dst[(n0 + ty + i) * 128 + (l0 + tx)] = tile[tx][ty + i];
}

// ---------------------------------------------------------------------------
// k6: zq1 multi-token. Block = 8 tokens x 64 h-cols; grid (4, 16, B).
// Phase 1: scores s[8 tok][128 m] (thread owns m, all 8 toks) -> masked P in LDS.
// Phase 2: u = W1 q, v = mW1 q (8x weight amortization) + P-contraction,
//          combine + silu -> XQ.
// ---------------------------------------------------------------------------
__global__ __launch_bounds__(128) void zq1_kernel(
    const float* __restrict__ b1, const float* __restrict__ mb1,
    float* __restrict__ ws) {
    int b = blockIdx.z;
    int l0 = blockIdx.y * 8;
    int c0 = blockIdx.x * 64;
    int t = threadIdx.x;
    __shared__ float qs[8][260];
    __shared__ float ps[8][132];
    for (int i = t; i < 512; i += 128) {
        int tok = i >> 6, kq = i & 63;
        *(float4*)&qs[tok][kq * 4] =
            *(const float4*)(ws + OFF_Q + (b * 128 + l0 + tok) * 256 + kq * 4);
    }
    __syncthreads();
    {   // phase 1: scores + P
        int m = t;  // 0..127
        float sv[8] = {0, 0, 0, 0, 0, 0, 0, 0};
        const float* KT = ws + OFF_KT + b * 32768;
#pragma unroll 4
        for (int d = 0; d < 256; ++d) {
            float kv = KT[d * 128 + m];
#pragma unroll
            for (int j = 0; j < 8; ++j) sv[j] += qs[j][d] * kv;
        }
        float lrm = ws[OFF_LR + b * 128 + m];
#pragma unroll
        for (int j = 0; j < 8; ++j) {
            int l = l0 + j;
            float p = 0.0f;
            if (m <= l)
                p = ws[OFF_A + (b * 128 + l) * 128 + m] * lrm * (1.0f + sv[j]);
            ps[j][m] = p;
        }
    }
    __syncthreads();
    // phase 2
    int tok = t >> 4, cq = t & 15;
    int c = c0 + 4 * cq;
    const float* W1t  = ws + OFF_W1T  + b * 65536 + c;
    const float* mW1t = ws + OFF_MW1T + b * 65536 + c;
    float4 au = {0, 0, 0, 0}, av = {0, 0, 0, 0};
#pragma unroll 4
    for (int d = 0; d < 256; ++d) {
        float qd = qs[tok][d];
        au = fma4(qd, *(const float4*)(W1t + d * 256), au);
        av = fma4(qd, *(const float4*)(mW1t + d * 256), av);
    }
    float4 ap = {0, 0, 0, 0};
    const float* gz1p = ws + OFF_GZ1 + b * 32768 + c;
    int mmax = l0 + 8;
#pragma unroll 4
    for (int m = 0; m < mmax; ++m)
        ap = fma4(ps[tok][m], *(const float4*)(gz1p + m * 256), ap);
    int l = l0 + tok;
    float cl = ws[OFF_C + b * 128 + l];
    float wd = ws[OFF_WDCUM + b * 128 + l];
    float4 mb = *(const float4*)(mb1 + b * 256 + c);
    float4 bb = *(const float4*)(b1 + b * 256 + c);
    float4 o;
    o.x = silu_f(ap.x - cl * (av.x + mb.x) + wd * (au.x + bb.x));
    o.y = silu_f(ap.y - cl * (av.y + mb.y) + wd * (au.y + bb.y));
    o.z = silu_f(ap.z - cl * (av.z + mb.z) + wd * (au.z + bb.z));
    o.w = silu_f(ap.w - cl * (av.w + mb.w) + wd * (au.w + bb.w));
    *(float4*)(ws + OFF_XQ + (b * 128 + l) * 256 + c) = o;
}

// ---------------------------------------------------------------------------
// k7: zq2 multi-token (same structure, no silu, writes out).
// ---------------------------------------------------------------------------
__global__ __launch_bounds__(128) void zq2_kernel(
    const float* __restrict__ b2, const float* __restrict__ mb2,
    float* __restrict__ out, float* __restrict__ ws) {
    int b = blockIdx.z;
    int l0 = blockIdx.y * 8;
    int c0 = blockIdx.x * 64;
    int t = threadIdx.x;
    __shared__ float xqs[8][260];
    __shared__ float ps[8][132];
    for (int i = t; i < 512; i += 128) {
        int tok = i >> 6, kq = i & 63;
        *(float4*)&xqs[tok][kq * 4] =
            *(const float4*)(ws + OFF_XQ + (b * 128 + l0 + tok) * 256 + kq * 4);
    }
    __syncthreads();
    {
        int m = t;
        float sv[8] = {0, 0, 0, 0, 0, 0, 0, 0};
        const float* X2t = ws + OFF_X2T + b * 32768;
#pragma unroll 4
        for (int h = 0; h < 256; ++h) {
            float xv = X2t[h * 128 + m];
#pragma unroll
            for (int j = 0; j < 8; ++j) sv[j] += xqs[j][h] * xv;
        }
        float lrm = ws[OFF_LR + b * 128 + m];
#pragma unroll
        for (int j = 0; j < 8; ++j) {
            int l = l0 + j;
            float p = 0.0f;
            if (m <= l)
                p = ws[OFF_A + (b * 128 + l) * 128 + m] * lrm * (1.0f + sv[j]);
            ps[j][m] = p;
        }
    }
    __syncthreads();
    int tok = t >> 4, cq = t & 15;
    int c = c0 + 4 * cq;
    const float* W2t  = ws + OFF_W2T  + b * 65536 + c;
    const float* mW2t = ws + OFF_MW2T + b * 65536 + c;
    float4 au = {0, 0, 0, 0}, av = {0, 0, 0, 0};
#pragma unroll 4
    for (int h = 0; h < 256; ++h) {
        float xh = xqs[tok][h];
        au = fma4(xh, *(const float4*)(W2t + h * 256), au);
        av = fma4(xh, *(const float4*)(mW2t + h * 256), av);
    }
    float4 ap = {0, 0, 0, 0};
    const float* gz2p = ws + OFF_GZ2 + b * 32768 + c;
    int mmax = l0 + 8;
#pragma unroll 4
    for (int m = 0; m < mmax; ++m)
        ap = fma4(ps[tok][m], *(const float4*)(gz2p + m * 256), ap);
    int l = l0 + tok;
    float cl = ws[OFF_C + b * 128 + l];
    float wd = ws[OFF_WDCUM + b * 128 + l];
    float4 mb = *(const float4*)(mb2 + b * 256 + c);
    float4 bb = *(const float4*)(b2 + b * 256 + c);
    float4 o;
    o.x = ap.x - cl * (av.x + mb.x) + wd * (au.x + bb.x);
    o.y = ap.y - cl * (av.y + mb.y) + wd * (au.y + bb.y);
    o.z = ap.z - cl * (av.z + mb.z) + wd * (au.z + bb.z);
    o.w = ap.w - cl * (av.w + mb.w) + wd * (au.w + bb.w);
    *(float4*)(out + OUT_ZQ2 + (b * 128 + l) * 256 + c) = o;
}

// ---------------------------------------------------------------------------
// k8: last-token weight outputs (W1p/mgW1 fam=0, W2p/mgW2 fam=1)
// ---------------------------------------------------------------------------
__global__ __launch_bounds__(256) void lastw_kernel(
    const float* __restrict__ W1, const float* __restrict__ mW1,
    const float* __restrict__ W2, const float* __restrict__ mW2,
    const float* __restrict__ ws, float* __restrict__ out) {
    int z = blockIdx.z; int b = z >> 1; int fam = z & 1;
    int t = threadIdx.x;
    __shared__ float wa[128], wm[128];
    __shared__ float LA[128][16], LM[128][16], R[128][16];
    const float* lr = ws + OFF_LR + b * Ln;
    const float* Pm = ws + OFF_PM + b * Ln;
    const float* Arow = ws + OFF_A + (b * Ln + Ln - 1) * Ln;
    if (t < 128) {
        wa[t] = Arow[t] * lr[t];
        wm[t] = expf(Pm[Ln - 1] - Pm[t]) * lr[t];
    }
    const float* left  = ws + (fam == 0 ? OFF_GZ1 : OFF_GZ2) + b * Ln * 256;
    const float* right = ws + (fam == 0 ? OFF_K   : OFF_X2 ) + b * Ln * 256;
    int i0 = blockIdx.y * 16, j0 = blockIdx.x * 16;
    __syncthreads();
    for (int e = t; e < 2048; e += 256) {
        int m = e >> 4, i = e & 15;
        float lv = left[m * 256 + i0 + i];
        LA[m][i] = wa[m] * lv;
        LM[m][i] = wm[m] * lv;
        R[m][i]  = right[m * 256 + j0 + i];
    }
    __syncthreads();
    int tx = t & 15, ty = t >> 4;
    float accA = 0.0f, accM = 0.0f;
#pragma unroll 4
    for (int m = 0; m < 128; ++m) {
        accA += LA[m][ty] * R[m][tx];
        accM += LM[m][ty] * R[m][tx];
    }
    float c_last  = ws[OFF_C + b * Ln + Ln - 1];
    float wd_last = ws[OFF_WDCUM + b * Ln + Ln - 1];
    float mc_last = ws[OFF_MOMCUM + b * Ln + Ln - 1];
    int i = i0 + ty, j = j0 + tx;
    const float* base1 = (fam == 0 ? W1 : W2) + b * 65536;
    const float* basem = (fam == 0 ? mW1 : mW2) + b * 65536;
    float b1v = base1[i * 256 + j], bmv = basem[i * 256 + j];
    int op = (fam == 0 ? OUT_W1P : OUT_W2P) + (b * 256 + i) * 256 + j;
    int om = (fam == 0 ? OUT_MGW1 : OUT_MGW2) + (b * 256 + i) * 256 + j;
    out[op] = accA - c_last * bmv + wd_last * b1v;
    out[om] = accM - mc_last * bmv;
}

// ---------------------------------------------------------------------------
// k9: last-token bias outputs
// ---------------------------------------------------------------------------
__global__ __launch_bounds__(256) void lastb_kernel(
    const float* __restrict__ b1, const float* __restrict__ mb1,
    const float* __restrict__ b2, const float* __restrict__ mb2,
    const float* __restrict__ ws, float* __restrict__ out) {
    int b = blockIdx.x; int t = threadIdx.x;
    __shared__ float wa[128], wm[128];
    if (t < 128) {
        wa[t] = ws[OFF_A + (b * Ln + Ln - 1) * Ln + t] * ws[OFF_LR + b * Ln + t];
        wm[t] = expf(ws[OFF_PM + b * Ln + Ln - 1] - ws[OFF_PM + b * Ln + t]) *
                ws[OFF_LR + b * Ln + t];
    }
    __syncthreads();
    const float* gz1 = ws + OFF_GZ1 + b * Ln * 256;
    const float* gz2 = ws + OFF_GZ2 + b * Ln * 256;
    float sA1 = 0, sM1 = 0, sA2 = 0, sM2 = 0;
#pragma unroll 4
    for (int m = 0; m < 128; ++m) {
        float g1 = gz1[m * 256 + t], g2 = gz2[m * 256 + t];
        sA1 += wa[m] * g1; sM1 += wm[m] * g1;
        sA2 += wa[m] * g2; sM2 += wm[m] * g2;
    }
    float c_last  = ws[OFF_C + b * Ln + Ln - 1];
    float wd_last = ws[OFF_WDCUM + b * Ln + Ln - 1];
    float mc_last = ws[OFF_MOMCUM + b * Ln + Ln - 1];
    out[OUT_B1P + b * 256 + t]  = sA1 - c_last * mb1[b * 256 + t] + wd_last * b1[b * 256 + t];
    out[OUT_MGB1 + b * 256 + t] = sM1 - mc_last * mb1[b * 256 + t];
    out[OUT_B2P + b * 256 + t]  = sA2 - c_last * mb2[b * 256 + t] + wd_last * b2[b * 256 + t];
    out[OUT_MGB2 + b * 256 + t] = sM2 - mc_last * mb2[b * 256 + t];
}

// ---------------------------------------------------------------------------
extern "C" void kernel_launch(void* const* d_in, const int* in_sizes, int n_in,
                              void* d_out, int out_size, void* d_ws, size_t ws_size,
                              hipStream_t stream) {
    const float* x   = (const float*)d_in[0];
    const float* Wq  = (const float*)d_in[1];
    const float* bq  = (const float*)d_in[2];
    const float* Wk  = (const float*)d_in[3];
    const float* bk  = (const float*)d_in[4];
    const float* Wv  = (const float*)d_in[5];
    const float* bv  = (const float*)d_in[6];
    const float* Wlr = (const float*)d_in[7];
    const float* blr = (const float*)d_in[8];
    const float* Wm  = (const float*)d_in[9];
    const float* bm  = (const float*)d_in[10];
    const float* Wd  = (const float*)d_in[11];
    const float* bd  = (const float*)d_in[12];
    const float* W1  = (const float*)d_in[13];
    const float* b1  = (const float*)d_in[14];
    const float* W2  = (const float*)d_in[15];
    const float* b2  = (const float*)d_in[16];
    const float* mW1 = (const float*)d_in[17];
    const float* mb1 = (const float*)d_in[18];
    const float* mW2 = (const float*)d_in[19];
    const float* mb2 = (const float*)d_in[20];
    float* ws  = (float*)d_ws;
    float* out = (float*)d_out;

    transpose_kernel<<<dim3(8, 8, 8), 256, 0, stream>>>(W1, W2, mW1, mW2, ws);
    qkv_kernel<<<dim3(4, 32, 3), 128, 0, stream>>>(x, Wq, bq, Wk, bk, Wv, bv, ws);
    scalproj_kernel<<<64, 256, 0, stream>>>(x, Wlr, blr, Wm, bm, Wd, bd, ws);
    scan_kernel<<<Bn, 128, 0, stream>>>(ws);
    a_kernel<<<Bn * Ln, 128, 0, stream>>>(ws);
    fstage_kernel<0><<<dim3(4, 32), 128, 0, stream>>>(W2, b1, b2, ws);
    fstage_kernel<1><<<dim3(4, 32), 128, 0, stream>>>(W2, b1, b2, ws);
    fstage_kernel<2><<<dim3(4, 32), 128, 0, stream>>>(W2, b1, b2, ws);
    transpkx_kernel<<<dim3(8, 4, 4), 256, 0, stream>>>(ws);
    zq1_kernel<<<dim3(4, 16, 2), 128, 0, stream>>>(b1, mb1, ws);
    zq2_kernel<<<dim3(4, 16, 2), 128, 0, stream>>>(b2, mb2, out, ws);
    lastw_kernel<<<dim3(16, 16, Bn * 2), 256, 0, stream>>>(W1, mW1, W2, mW2, ws, out);
    lastb_kernel<<<Bn, 256, 0, stream>>>(b1, mb1, b2, mb2, ws, out);
}